// Round 1
// baseline (823.618 us; speedup 1.0000x reference)
//
#include <hip/hip_runtime.h>
#include <math.h>

#define NCH   32
#define NCLS  8
#define NPIX  (8 * 256 * 256)          // B*H*W pixels
#define TRI   528                      // 32*33/2 packed lower-triangular

// Per-launch precomputed constants (rewritten every kernel_launch; no ws needed).
__device__ float g_tri[NCLS * TRI];    // packed rows of Linv_k (lower tri)
__device__ float g_offn[NCLS * NCH];   // -(Linv_k @ mean_k)
__device__ float g_lc2[NCLS];          // (-16*ln(2pi) - logdet_k) * log2(e)
__device__ float g_gauss[(size_t)NPIX * NCLS];  // 16 MiB: normalized class weights g[p][k]

// ---------------------------------------------------------------------------
// Setup: invert the 8 lower-triangular 32x32 factors (fp64 forward
// substitution, one thread per (class, column)), fold mean and log-det.
// ---------------------------------------------------------------------------
__global__ __launch_bounds__(256) void setup_kernel(const float* __restrict__ mean,
                                                    const float* __restrict__ scale) {
  __shared__ float sinv[NCLS][NCH][NCH];
  const int t = threadIdx.x;
  const int k = t >> 5;                // class
  const int j = t & 31;                // column of Linv
  const float* L = scale + k * NCH * NCH;

  double y[NCH];
  #pragma unroll
  for (int i = 0; i < NCH; ++i) {
    double s = (i == j) ? 1.0 : 0.0;
    #pragma unroll
    for (int m = 0; m < i; ++m) s -= (double)L[i * NCH + m] * y[m];
    y[i] = (i < j) ? 0.0 : (s / (double)L[i * NCH + i]);
  }
  #pragma unroll
  for (int i = 0; i < NCH; ++i) sinv[k][i][j] = (float)y[i];
  __syncthreads();

  // thread (k, j) now handles row j of class k
  {
    const int base = k * TRI + j * (j + 1) / 2;
    for (int m = 0; m <= j; ++m) g_tri[base + m] = sinv[k][j][m];
  }
  {
    double o = 0.0;
    for (int m = 0; m <= j; ++m) o += (double)sinv[k][j][m] * (double)mean[k * NCH + m];
    g_offn[k * NCH + j] = (float)(-o);
  }
  if (j == 0) {
    double ld = 0.0;
    for (int i = 0; i < NCH; ++i) ld += log(fabs((double)L[i * NCH + i]));
    const double LOG_2PI = 1.8378770664093454836;
    const double LOG2E   = 1.4426950408889634074;
    g_lc2[k] = (float)((-0.5 * NCH * LOG_2PI - ld) * LOG2E);
  }
}

// ---------------------------------------------------------------------------
// Stage 1: VALU-bound. Per pixel: 8 triangular matvecs -> probs -> normalized
// class weights g[p][0..7] written to g_gauss (16 MiB). LDS-transposed x stage
// identical to the proven fused kernel. Probs round-trip through a stride-9
// LDS row (same thread, no barrier) to avoid a runtime-indexed register array.
// ---------------------------------------------------------------------------
__global__ __launch_bounds__(256, 3) void gauss_kernel(const float* __restrict__ x) {
  __shared__ float xs[256 * NCH];      // 32 KB, swizzled float4 slots
  __shared__ float gs[256 * 9];        // prob scratch, stride 9 (9.2 KB)
  const int t = threadIdx.x;
  const long long pixBase = (long long)blockIdx.x * 256;

  // Phase A: fully coalesced global -> LDS stage of the block's 256 pixel rows
  {
    const float4* gx = reinterpret_cast<const float4*>(x + pixBase * NCH);
    #pragma unroll
    for (int i = 0; i < 8; ++i) {
      const float4 v = gx[i * 256 + t];
      const int p = i * 32 + (t >> 3); // pixel-in-block this float4 belongs to
      const int c = t & 7;             // chunk index within the pixel row
      reinterpret_cast<float4*>(xs)[p * 8 + (c ^ (p & 7))] = v;
    }
  }
  __syncthreads();

  // Phase B: own row -> registers (swizzle-aware, conflict-spread b128 reads)
  float xv[NCH];
  {
    const float4* row = reinterpret_cast<const float4*>(xs + t * NCH);
    #pragma unroll
    for (int i = 0; i < 8; ++i) {
      const float4 v = row[i ^ (t & 7)];
      xv[4 * i + 0] = v.x; xv[4 * i + 1] = v.y;
      xv[4 * i + 2] = v.z; xv[4 * i + 3] = v.w;
    }
  }

  // Phase C: 8 triangular matvecs; all coefficients wave-uniform (SGPR loads)
  float s2 = 0.0f;
  #pragma unroll 1                      // keep k-loop rolled: ~4.5KB body, I$-friendly
  for (int k = 0; k < NCLS; ++k) {
    const float* __restrict__ tri  = g_tri  + k * TRI;
    const float* __restrict__ offn = g_offn + k * NCH;
    float maha = 0.0f;
    int idx = 0;
    #pragma unroll
    for (int c = 0; c < NCH; ++c) {
      float z = offn[c];               // = -(Linv@mean)[c]
      #pragma unroll
      for (int m = 0; m <= c; ++m) z = fmaf(tri[idx + m], xv[m], z);
      idx += c + 1;
      maha = fmaf(z, z, maha);
    }
    // prob = exp(-0.5*maha - 16*ln(2pi) - logdet) via exp2
    const float p = exp2f(fmaf(maha, -0.72134752044448170368f, g_lc2[k]));
    gs[t * 9 + k] = p;
    s2 = fmaf(p, p, s2);
  }
  const float rinv = rsqrtf(fmaxf(s2, 1e-12f));

  // Write normalized weights: 32 B/thread -> two half-dense dwordx4 streams,
  // adjacent in L2 (16 MiB total, negligible vs the 512 MiB stage-2 write).
  float4 a, b;
  a.x = gs[t * 9 + 0] * rinv; a.y = gs[t * 9 + 1] * rinv;
  a.z = gs[t * 9 + 2] * rinv; a.w = gs[t * 9 + 3] * rinv;
  b.x = gs[t * 9 + 4] * rinv; b.y = gs[t * 9 + 5] * rinv;
  b.z = gs[t * 9 + 6] * rinv; b.w = gs[t * 9 + 7] * rinv;
  float4* gp = reinterpret_cast<float4*>(g_gauss + (pixBase + t) * NCLS);
  gp[0] = a; gp[1] = b;
}

// ---------------------------------------------------------------------------
// Stage 2: pure streaming expand, fill-kernel-shaped. No LDS, no barriers,
// full occupancy. One pixel per wave-iteration: lane l emits out[p][l*4..l*4+4)
// = g[p][l>>3] * x[p][(l&7)*4..+4). Wave reads 128B (x) + 32B (g) broadcasts,
// stores 1 KB coalesced. 64 consecutive pixels per wave -> 64 KB contiguous
// write region per wave, 256 KB per block.
// ---------------------------------------------------------------------------
__global__ __launch_bounds__(256) void expand_kernel(const float* __restrict__ x,
                                                     float* __restrict__ out) {
  const int wid  = (blockIdx.x << 2) | (threadIdx.x >> 6);  // global wave id
  const int lane = threadIdx.x & 63;
  const int kk   = lane >> 3;          // class for this lane's chunk
  const int ch   = lane & 7;           // float4 chunk of x
  const long long p0 = (long long)wid * 64;                 // 64 pixels per wave

  const float4* __restrict__ x4 = reinterpret_cast<const float4*>(x) + p0 * 8 + ch;
  const float*  __restrict__ gp = g_gauss + p0 * NCLS + kk;
  float* __restrict__ op = out + p0 * (NCLS * NCH) + (lane << 2);

  #pragma unroll 4
  for (int i = 0; i < 64; ++i) {
    const float4 xc = x4[i * 8];
    const float  gv = gp[i * 8];
    float4 o;
    o.x = gv * xc.x; o.y = gv * xc.y; o.z = gv * xc.z; o.w = gv * xc.w;
    *reinterpret_cast<float4*>(op + (long long)i * (NCLS * NCH)) = o;
  }
}

// ---------------------------------------------------------------------------
extern "C" void kernel_launch(void* const* d_in, const int* in_sizes, int n_in,
                              void* d_out, int out_size, void* d_ws, size_t ws_size,
                              hipStream_t stream) {
  const float* x     = (const float*)d_in[0];  // [8,256,256,32]
  const float* mean  = (const float*)d_in[1];  // [8,32]
  const float* scale = (const float*)d_in[2];  // [8,32,32]
  float* out = (float*)d_out;                  // [8,256,256,256]

  hipLaunchKernelGGL(setup_kernel, dim3(1), dim3(256), 0, stream, mean, scale);
  hipLaunchKernelGGL(gauss_kernel, dim3(NPIX / 256), dim3(256), 0, stream, x);
  hipLaunchKernelGGL(expand_kernel, dim3(NPIX / 256), dim3(256), 0, stream, x, out);
}

// Round 2
// 736.192 us; speedup vs baseline: 1.1188x; 1.1188x over previous
//
#include <hip/hip_runtime.h>
#include <math.h>

#define NCH   32
#define NCLS  8
#define NPIX  (8 * 256 * 256)          // B*H*W pixels
#define TRI   528                      // 32*33/2 packed lower-triangular

// Per-launch precomputed constants (rewritten every kernel_launch; no ws needed).
__device__ float g_tri[NCLS * TRI];    // packed rows of Linv_k (lower tri)
__device__ float g_offn[NCLS * NCH];   // -(Linv_k @ mean_k)
__device__ float g_lc2[NCLS];          // (-16*ln(2pi) - logdet_k) * log2(e)

// ---------------------------------------------------------------------------
// Setup: invert the 8 lower-triangular 32x32 factors (fp64 forward
// substitution, one thread per (class, column)), fold mean and log-det.
// ---------------------------------------------------------------------------
__global__ __launch_bounds__(256) void setup_kernel(const float* __restrict__ mean,
                                                    const float* __restrict__ scale) {
  __shared__ float sinv[NCLS][NCH][NCH];
  const int t = threadIdx.x;
  const int k = t >> 5;                // class
  const int j = t & 31;                // column of Linv
  const float* L = scale + k * NCH * NCH;

  double y[NCH];
  #pragma unroll
  for (int i = 0; i < NCH; ++i) {
    double s = (i == j) ? 1.0 : 0.0;
    #pragma unroll
    for (int m = 0; m < i; ++m) s -= (double)L[i * NCH + m] * y[m];
    y[i] = (i < j) ? 0.0 : (s / (double)L[i * NCH + i]);
  }
  #pragma unroll
  for (int i = 0; i < NCH; ++i) sinv[k][i][j] = (float)y[i];
  __syncthreads();

  // thread (k, j) now handles row j of class k
  {
    const int base = k * TRI + j * (j + 1) / 2;
    for (int m = 0; m <= j; ++m) g_tri[base + m] = sinv[k][j][m];
  }
  {
    double o = 0.0;
    for (int m = 0; m <= j; ++m) o += (double)sinv[k][j][m] * (double)mean[k * NCH + m];
    g_offn[k * NCH + j] = (float)(-o);
  }
  if (j == 0) {
    double ld = 0.0;
    for (int i = 0; i < NCH; ++i) ld += log(fabs((double)L[i * NCH + i]));
    const double LOG_2PI = 1.8378770664093454836;
    const double LOG2E   = 1.4426950408889634074;
    g_lc2[k] = (float)((-0.5 * NCH * LOG_2PI - ld) * LOG2E);
  }
}

// ---------------------------------------------------------------------------
// Fused main, v2: P=4 pixels/thread so each LDS-broadcast coefficient feeds
// 4 FMA streams (phase C was coefficient-load-bound, not FMA-bound).
// Coefficients live in LDS (staged once; removes scalar-K$ thrash).
// Waves free-run after the single coefficient barrier: per-wave prob/x slabs,
// so late waves' compute overlaps early waves' coalesced store stream.
// Block = 256 thr = 4 waves; wave owns 256 contiguous pixels (4 chunks x 64).
// LDS: ctri 16.5K + coffn 1K + gsw 36K + xslab 16K = 69.5 KB -> 2 blocks/CU.
// ---------------------------------------------------------------------------
__global__ __launch_bounds__(256, 2) void fuzzy_main(const float* __restrict__ x,
                                                     float* __restrict__ out) {
  __shared__ float  ctri[NCLS * TRI];       // 16896 B, packed rows of Linv
  __shared__ float  coffn[NCLS * NCH];      // 1024 B
  __shared__ float  clc2[NCLS];             // 32 B
  __shared__ float  gsw[4][256 * 9];        // per-wave prob slabs (stride 9: conflict-free)
  __shared__ float4 xslab[4][32 * 8];       // per-wave 32-pixel x slab for epilogue transpose

  const int t = threadIdx.x;
  const int w = t >> 6;                     // wave in block
  const int l = t & 63;                     // lane

  // Stage coefficients cooperatively (global -> LDS, L2-warm after block 0)
  for (int i = t; i < NCLS * TRI; i += 256) ctri[i] = g_tri[i];
  if (t < NCLS * NCH) coffn[t] = g_offn[t];
  if (t < NCLS)       clc2[t]  = g_lc2[t];

  // Phase AB: direct global -> registers. Wave w owns pixels [pixW, pixW+256).
  // Per instruction lanes stride 128B over an 8KB window; all bytes consumed
  // across the 8 chunk-loads -> L1-resident, no LDS round-trip needed.
  const long long pixW = (long long)blockIdx.x * 1024 + (long long)w * 256;
  float xv[4][NCH];
  {
    const float4* __restrict__ x4 = reinterpret_cast<const float4*>(x) + pixW * 8;
    #pragma unroll
    for (int j = 0; j < 4; ++j) {
      #pragma unroll
      for (int c = 0; c < 8; ++c) {
        const float4 v = x4[(j * 64 + l) * 8 + c];
        xv[j][c * 4 + 0] = v.x; xv[j][c * 4 + 1] = v.y;
        xv[j][c * 4 + 2] = v.z; xv[j][c * 4 + 3] = v.w;
      }
    }
  }
  __syncthreads();                          // coefficients visible; waves free-run after

  // Phase C: 8 classes x (528-FMA triangular matvec x 4 pixels).
  // Coefficient reads are wave-uniform LDS broadcasts shared by 4 FMA streams.
  float* __restrict__ gslab = gsw[w];
  float s2_0 = 0.f, s2_1 = 0.f, s2_2 = 0.f, s2_3 = 0.f;
  #pragma unroll 1                          // keep k rolled: ~20KB body fits I$
  for (int k = 0; k < NCLS; ++k) {
    const float* __restrict__ tri = ctri  + k * TRI;
    const float* __restrict__ off = coffn + k * NCH;
    const float lk = clc2[k];
    float mh0 = 0.f, mh1 = 0.f, mh2 = 0.f, mh3 = 0.f;
    int idx = 0;
    #pragma unroll
    for (int c = 0; c < NCH; ++c) {
      const float o = off[c];
      float z0 = o, z1 = o, z2 = o, z3 = o;
      #pragma unroll
      for (int m = 0; m <= c; ++m) {
        const float a = tri[idx + m];
        z0 = fmaf(a, xv[0][m], z0);
        z1 = fmaf(a, xv[1][m], z1);
        z2 = fmaf(a, xv[2][m], z2);
        z3 = fmaf(a, xv[3][m], z3);
      }
      idx += c + 1;
      mh0 = fmaf(z0, z0, mh0); mh1 = fmaf(z1, z1, mh1);
      mh2 = fmaf(z2, z2, mh2); mh3 = fmaf(z3, z3, mh3);
    }
    const float CEXP = -0.72134752044448170368f;  // -0.5*log2(e)
    const float p0 = exp2f(fmaf(mh0, CEXP, lk));
    const float p1 = exp2f(fmaf(mh1, CEXP, lk));
    const float p2 = exp2f(fmaf(mh2, CEXP, lk));
    const float p3 = exp2f(fmaf(mh3, CEXP, lk));
    gslab[(0 * 64 + l) * 9 + k] = p0;
    gslab[(1 * 64 + l) * 9 + k] = p1;
    gslab[(2 * 64 + l) * 9 + k] = p2;
    gslab[(3 * 64 + l) * 9 + k] = p3;
    s2_0 = fmaf(p0, p0, s2_0); s2_1 = fmaf(p1, p1, s2_1);
    s2_2 = fmaf(p2, p2, s2_2); s2_3 = fmaf(p3, p3, s2_3);
  }
  gslab[(0 * 64 + l) * 9 + 8] = rsqrtf(fmaxf(s2_0, 1e-12f));
  gslab[(1 * 64 + l) * 9 + 8] = rsqrtf(fmaxf(s2_1, 1e-12f));
  gslab[(2 * 64 + l) * 9 + 8] = rsqrtf(fmaxf(s2_2, 1e-12f));
  gslab[(3 * 64 + l) * 9 + 8] = rsqrtf(fmaxf(s2_3, 1e-12f));

  // Epilogue (wave-private, no barriers): 8 half-chunks of 32 pixels.
  // Owning half-wave deposits its x rows into the wave slab (swizzled), then
  // all 64 lanes emit 1KB-coalesced stores: lane l -> out[p][l*4..l*4+4) =
  // g[p][l>>3] * x[p][(l&7)*4..+4). Compile-time j/half keeps xv[] in regs.
  float4* __restrict__ xsl = xslab[w];
  const int ch = l & 7;
  const int kk = l >> 3;
  #pragma unroll
  for (int j = 0; j < 4; ++j) {
    #pragma unroll
    for (int half = 0; half < 2; ++half) {
      if ((l >> 5) == half) {
        const int r = l & 31;
        #pragma unroll
        for (int c = 0; c < 8; ++c) {
          float4 v;
          v.x = xv[j][c * 4 + 0]; v.y = xv[j][c * 4 + 1];
          v.z = xv[j][c * 4 + 2]; v.w = xv[j][c * 4 + 3];
          xsl[r * 8 + (c ^ (r & 7))] = v;   // same swizzle as the read below
        }
      }
      // wave-local LDS RAW across lanes: drain ds_writes before cross-lane reads
      asm volatile("s_waitcnt lgkmcnt(0)" ::: "memory");

      const int pbase = j * 64 + half * 32;           // pixel idx within wave slab
      float* ob = out + (pixW + pbase) * (NCLS * NCH) + (l << 2);
      #pragma unroll 4
      for (int i = 0; i < 32; ++i) {
        const int pw = pbase + i;
        const float g = gsw[w][pw * 9 + kk] * gsw[w][pw * 9 + 8];  // broadcast reads
        const float4 xc = xsl[i * 8 + (ch ^ (i & 7))];             // broadcast read
        float4 o;
        o.x = g * xc.x; o.y = g * xc.y; o.z = g * xc.z; o.w = g * xc.w;
        *reinterpret_cast<float4*>(ob + (long long)i * (NCLS * NCH)) = o;
      }
      // reads of xsl complete before the next half-chunk overwrites it
      asm volatile("s_waitcnt lgkmcnt(0)" ::: "memory");
    }
  }
}

// ---------------------------------------------------------------------------
extern "C" void kernel_launch(void* const* d_in, const int* in_sizes, int n_in,
                              void* d_out, int out_size, void* d_ws, size_t ws_size,
                              hipStream_t stream) {
  const float* x     = (const float*)d_in[0];  // [8,256,256,32]
  const float* mean  = (const float*)d_in[1];  // [8,32]
  const float* scale = (const float*)d_in[2];  // [8,32,32]
  float* out = (float*)d_out;                  // [8,256,256,256]

  hipLaunchKernelGGL(setup_kernel, dim3(1), dim3(256), 0, stream, mean, scale);
  hipLaunchKernelGGL(fuzzy_main, dim3(NPIX / 1024), dim3(256), 0, stream, x, out);
}

// Round 3
// 652.492 us; speedup vs baseline: 1.2623x; 1.1283x over previous
//
#include <hip/hip_runtime.h>
#include <math.h>

#define NCH   32
#define NCLS  8
#define NPIX  (8 * 256 * 256)          // B*H*W pixels
#define TRI   528                      // 32*33/2 packed lower-triangular

// Per-launch precomputed constants (rewritten every kernel_launch; no ws needed).
__device__ float g_tri[NCLS * TRI];    // packed rows of Linv_k (lower tri)
__device__ float g_offn[NCLS * NCH];   // -(Linv_k @ mean_k)
__device__ float g_lc2[NCLS];          // (-16*ln(2pi) - logdet_k) * log2(e)

// ---------------------------------------------------------------------------
// Setup: invert the 8 lower-triangular 32x32 factors (fp64 forward
// substitution, one thread per (class, column)), fold mean and log-det.
// ---------------------------------------------------------------------------
__global__ __launch_bounds__(256) void setup_kernel(const float* __restrict__ mean,
                                                    const float* __restrict__ scale) {
  __shared__ float sinv[NCLS][NCH][NCH];
  const int t = threadIdx.x;
  const int k = t >> 5;                // class
  const int j = t & 31;                // column of Linv
  const float* L = scale + k * NCH * NCH;

  double y[NCH];
  #pragma unroll
  for (int i = 0; i < NCH; ++i) {
    double s = (i == j) ? 1.0 : 0.0;
    #pragma unroll
    for (int m = 0; m < i; ++m) s -= (double)L[i * NCH + m] * y[m];
    y[i] = (i < j) ? 0.0 : (s / (double)L[i * NCH + i]);
  }
  #pragma unroll
  for (int i = 0; i < NCH; ++i) sinv[k][i][j] = (float)y[i];
  __syncthreads();

  // thread (k, j) now handles row j of class k
  {
    const int base = k * TRI + j * (j + 1) / 2;
    for (int m = 0; m <= j; ++m) g_tri[base + m] = sinv[k][j][m];
  }
  {
    double o = 0.0;
    for (int m = 0; m <= j; ++m) o += (double)sinv[k][j][m] * (double)mean[k * NCH + m];
    g_offn[k * NCH + j] = (float)(-o);
  }
  if (j == 0) {
    double ld = 0.0;
    for (int i = 0; i < NCH; ++i) ld += log(fabs((double)L[i * NCH + i]));
    const double LOG_2PI = 1.8378770664093454836;
    const double LOG2E   = 1.4426950408889634074;
    g_lc2[k] = (float)((-0.5 * NCH * LOG_2PI - ld) * LOG2E);
  }
}

// ---------------------------------------------------------------------------
// Main v3 = round-0 kernel (best known) + ONE change: phase-C coefficients
// are staged once into LDS and read as wave-uniform broadcast ds_reads,
// instead of cycling 18 KB of wave-uniform global data through the scalar
// K$ (16 KB) every class iteration. LDS 41->59 KB, occupancy 3->2 blocks/CU
// (phase C is VALU-saturated at 2 waves/SIMD; store drain fine at 8 waves/CU).
// ---------------------------------------------------------------------------
__global__ __launch_bounds__(256, 2) void fuzzy_main(const float* __restrict__ x,
                                                     float* __restrict__ out) {
  __shared__ float xs[256 * NCH];      // 32 KB, swizzled float4 slots
  __shared__ float gs[256 * 9];        // prob[8] + inv per pixel, stride 9 (9 KB)
  __shared__ float ctri[NCLS * TRI];   // 16.9 KB packed Linv rows
  __shared__ float coffn[NCLS * NCH];  // 1 KB
  __shared__ float clc2[NCLS];         // 32 B
  const int t = threadIdx.x;
  const long long pixBase = (long long)blockIdx.x * 256;

  // Stage coefficients (L2-hot after block 0); overlaps with phase A loads.
  for (int i = t; i < NCLS * TRI; i += 256) ctri[i] = g_tri[i];
  if (t < NCLS * NCH) coffn[t] = g_offn[t];
  if (t < NCLS)       clc2[t]  = g_lc2[t];

  // Phase A: fully coalesced global -> LDS stage of the block's 256 pixel rows
  {
    const float4* gx = reinterpret_cast<const float4*>(x + pixBase * NCH);
    #pragma unroll
    for (int i = 0; i < 8; ++i) {
      const float4 v = gx[i * 256 + t];
      const int p = i * 32 + (t >> 3); // pixel-in-block this float4 belongs to
      const int c = t & 7;             // chunk index within the pixel row
      reinterpret_cast<float4*>(xs)[p * 8 + (c ^ (p & 7))] = v;
    }
  }
  __syncthreads();

  // Phase B: own row -> registers (swizzle-aware, conflict-spread b128 reads)
  float xv[NCH];
  {
    const float4* row = reinterpret_cast<const float4*>(xs + t * NCH);
    #pragma unroll
    for (int i = 0; i < 8; ++i) {
      const float4 v = row[i ^ (t & 7)];
      xv[4 * i + 0] = v.x; xv[4 * i + 1] = v.y;
      xv[4 * i + 2] = v.z; xv[4 * i + 3] = v.w;
    }
  }

  // Phase C: 8 triangular matvecs; coefficients are same-address LDS
  // broadcasts (conflict-free) shared by all 64 lanes.
  float s2 = 0.0f;
  #pragma unroll 1                      // keep k-loop rolled: I$-friendly
  for (int k = 0; k < NCLS; ++k) {
    const float* __restrict__ tri  = ctri  + k * TRI;
    const float* __restrict__ offn = coffn + k * NCH;
    float maha = 0.0f;
    int idx = 0;
    #pragma unroll
    for (int c = 0; c < NCH; ++c) {
      float z = offn[c];               // = -(Linv@mean)[c]
      #pragma unroll
      for (int m = 0; m <= c; ++m) z = fmaf(tri[idx + m], xv[m], z);
      idx += c + 1;
      maha = fmaf(z, z, maha);
    }
    // prob = exp(-0.5*maha - 16*ln(2pi) - logdet) via exp2
    const float p = exp2f(fmaf(maha, -0.72134752044448170368f, clc2[k]));
    gs[t * 9 + k] = p;
    s2 = fmaf(p, p, s2);
  }
  gs[t * 9 + 8] = rsqrtf(fmaxf(s2, 1e-12f));
  __syncthreads();

  // Phase D: epilogue. One pixel per wave-iteration; lane l emits elements
  // [l*4, l*4+4) of that pixel's 256-float output row -> 1KB coalesced store.
  const int lane = t & 63;
  const int w    = t >> 6;
  const int kk   = lane >> 3;          // class for this lane's chunk
  const int ch   = lane & 7;           // float4 chunk of x
  float* ob = out + (pixBase + (long long)w * 64) * (NCLS * NCH) + lane * 4;
  #pragma unroll 4
  for (int i = 0; i < 64; ++i) {
    const int p = w * 64 + i;
    const float g = gs[p * 9 + kk] * gs[p * 9 + 8];   // prob * rsqrt-norm (broadcast reads)
    const float4 xc = reinterpret_cast<const float4*>(xs)[p * 8 + (ch ^ (p & 7))];
    float4 o;
    o.x = g * xc.x; o.y = g * xc.y; o.z = g * xc.z; o.w = g * xc.w;
    *reinterpret_cast<float4*>(ob) = o;
    ob += NCLS * NCH;
  }
}

// ---------------------------------------------------------------------------
extern "C" void kernel_launch(void* const* d_in, const int* in_sizes, int n_in,
                              void* d_out, int out_size, void* d_ws, size_t ws_size,
                              hipStream_t stream) {
  const float* x     = (const float*)d_in[0];  // [8,256,256,32]
  const float* mean  = (const float*)d_in[1];  // [8,32]
  const float* scale = (const float*)d_in[2];  // [8,32,32]
  float* out = (float*)d_out;                  // [8,256,256,256]

  hipLaunchKernelGGL(setup_kernel, dim3(1), dim3(256), 0, stream, mean, scale);
  hipLaunchKernelGGL(fuzzy_main, dim3(NPIX / 256), dim3(256), 0, stream, x, out);
}